// Round 1
// baseline (24225.726 us; speedup 1.0000x reference)
//
#include <hip/hip_runtime.h>
#include <math.h>

#define T_LEN 2048
#define B_SZ  32
#define D_IN  128
#define U_SZ  512
#define N_SZ  256
#define GS    64
#define NT    256

// workspace offsets (in floats)
constexpr size_t OFF_AM  = 0;                                  // Am [256][256]
constexpr size_t OFF_WMM = OFF_AM  + (size_t)N_SZ*N_SZ;        // Wmm [256][512]
constexpr size_t OFF_BW  = OFF_WMM + (size_t)N_SZ*U_SZ;        // bw [512]
constexpr size_t OFF_UX  = OFF_BW  + U_SZ;                     // ux [2048][32]
constexpr size_t OFF_XT  = OFF_UX  + (size_t)T_LEN*B_SZ;       // xT [2048][128][32]
constexpr size_t OFF_S   = OFF_XT  + (size_t)T_LEN*D_IN*B_SZ;  // S [2][768][32]
constexpr size_t OFF_SS  = OFF_S   + (size_t)2*768*B_SZ;       // s_slots [3][32]
constexpr size_t OFF_BAR = OFF_SS  + 96;                       // barrier counter

#define FMA4(A, S0, W0) \
  A.x = fmaf(S0, W0.x, A.x); A.y = fmaf(S0, W0.y, A.y); \
  A.z = fmaf(S0, W0.z, A.z); A.w = fmaf(S0, W0.w, A.w);

// Am[k][j] = AT[k][j] + I + me[k]*BT[j]   (folds m@me term of u into the m-recurrence)
__global__ void k_am(const float* __restrict__ AT, const float* __restrict__ me,
                     const float* __restrict__ BT, float* __restrict__ ws) {
  int k = blockIdx.x, j = threadIdx.x;
  float v = AT[(size_t)k*N_SZ + j] + (k == j ? 1.0f : 0.0f) + me[k]*BT[j];
  ws[OFF_AM + (size_t)k*N_SZ + j] = v;
}

// bw[j] = sum_q BT[q]*Wm[q][j]
__global__ void k_bw(const float* __restrict__ BT, const float* __restrict__ Wm,
                     float* __restrict__ ws) {
  int j = blockIdx.x*256 + threadIdx.x;
  float acc = 0.f;
  for (int q = 0; q < N_SZ; ++q) acc += BT[q]*Wm[(size_t)q*U_SZ + j];
  ws[OFF_BW + j] = acc;
}

// Wmm = Am @ Wm   [256][512]
__global__ void k_wmm(const float* __restrict__ Wm, float* __restrict__ ws) {
  __shared__ float amr[N_SZ];
  int k = blockIdx.x, tid = threadIdx.x;
  amr[tid] = ws[OFF_AM + (size_t)k*N_SZ + tid];
  __syncthreads();
  float acc0 = 0.f, acc1 = 0.f;
  for (int q = 0; q < N_SZ; ++q) {
    float a = amr[q];
    acc0 += a * Wm[(size_t)q*U_SZ + tid];
    acc1 += a * Wm[(size_t)q*U_SZ + tid + 256];
  }
  ws[OFF_WMM + (size_t)k*U_SZ + tid]       = acc0;
  ws[OFF_WMM + (size_t)k*U_SZ + tid + 256] = acc1;
}

// ux[t][b] = x[b][t][:] . ie
__global__ void k_ux(const float* __restrict__ x, const float* __restrict__ ie,
                     float* __restrict__ ws) {
  __shared__ __align__(16) float iel[D_IN];
  __shared__ float red[B_SZ*9];
  int t = blockIdx.x, tid = threadIdx.x;
  if (tid < D_IN) iel[tid] = ie[tid];
  __syncthreads();
  int b = tid >> 3, p = tid & 7;
  const float4* xr = (const float4*)(x + ((size_t)b*T_LEN + t)*D_IN);
  const float4* wr = (const float4*)iel;
  float s = 0.f;
  for (int q = 0; q < 4; ++q) {
    int fi = p + q*8;
    float4 v = xr[fi];
    float4 w = wr[fi];
    s += v.x*w.x + v.y*w.y + v.z*w.z + v.w*w.w;
  }
  red[b*9 + p] = s;
  __syncthreads();
  if (tid < B_SZ) {
    float acc = 0.f;
    for (int p2 = 0; p2 < 8; ++p2) acc += red[tid*9 + p2];
    ws[OFF_UX + (size_t)t*B_SZ + tid] = acc;
  }
}

// xT[t][d][b] = x[b][t][d]  (LDS tile transpose)
__global__ void k_xt(const float* __restrict__ x, float* __restrict__ ws) {
  __shared__ float tile[B_SZ*33];
  int bid = blockIdx.x;
  int t = bid >> 2, d0 = (bid & 3)*32;
  int tid = threadIdx.x;
  int lo = tid & 31, hi = tid >> 5;
  for (int p = 0; p < 4; ++p) {
    int b = hi + p*8;
    tile[b*33 + lo] = x[((size_t)b*T_LEN + t)*D_IN + d0 + lo];
  }
  __syncthreads();
  float* dst = ws + OFF_XT + ((size_t)t*D_IN + d0)*B_SZ;
  for (int p = 0; p < 4; ++p) {
    int d = hi + p*8;
    dst[(size_t)d*B_SZ + lo] = tile[lo*33 + d];
  }
}

// init S[0] = [h0 | m0] transposed to [k][b]; s_slots; barrier counter
__global__ void k_init(const float* __restrict__ h0, const float* __restrict__ mm0,
                       const float* __restrict__ he, float* __restrict__ ws) {
  int bid = blockIdx.x, tid = threadIdx.x;
  if (bid < 24) {
    for (int i = 0; i < 4; ++i) {
      int e = bid*1024 + i*256 + tid;
      int k = e >> 5, b = e & 31;
      float v = (k < U_SZ) ? h0[(size_t)b*U_SZ + k] : mm0[(size_t)b*N_SZ + (k - U_SZ)];
      ws[OFF_S + e] = v;
    }
  } else {
    __shared__ float red[B_SZ*9];
    int b = tid >> 3, p = tid & 7;
    float s = 0.f;
    for (int i = 0; i < 64; ++i) {
      int k = p*64 + i;
      s += h0[(size_t)b*U_SZ + k] * he[k];
    }
    red[b*9 + p] = s;
    __syncthreads();
    if (tid < B_SZ) {
      float acc = 0.f;
      for (int p2 = 0; p2 < 8; ++p2) acc += red[tid*9 + p2];
      ws[OFF_SS + tid]      = ws[OFF_UX + tid] + acc;       // slot0 = ux[0] + h0.he
      ws[OFF_SS + 32 + tid] = ws[OFF_UX + B_SZ + tid];      // slot1 = ux[1]
      ws[OFF_SS + 64 + tid] = 0.0f;
    }
    if (tid == 128) {
      unsigned* cnt = (unsigned*)(ws + OFF_BAR);
      cnt[0] = 0u;
    }
  }
}

// persistent scan: G=64 blocks, each owns 8 h-cols + 4 m-cols; weights in LDS;
// state [768][32] double-buffered in global; 1 grid barrier per step.
__global__ __launch_bounds__(NT, 1) void k_scan(
    const float* __restrict__ Wh, const float* __restrict__ Wi,
    const float* __restrict__ he, const float* __restrict__ btv,
    float* __restrict__ ws, float* __restrict__ out)
{
  const int g = blockIdx.x, tid = threadIdx.x;
  const int JH = g*8, JM = g*4;
  const int bt = tid & 7, jt = (tid >> 3) & 1, ks = tid >> 4;
  const int b0 = bt*4;

  float* Amw = ws + OFF_AM;
  float* Wmm = ws + OFF_WMM;
  float* bww = ws + OFF_BW;
  float* uxw = ws + OFF_UX;
  float* xT  = ws + OFF_XT;
  float* Sb  = ws + OFF_S;
  float* ss  = ws + OFF_SS;
  unsigned* cnt = (unsigned*)(ws + OFF_BAR);

  __shared__ __align__(16) float Wl[896*8];     // [k][jj]: k<512 Wh, <768 Wmm, <896 Wi
  __shared__ __align__(16) float Aml[N_SZ*4];   // [k][jj] m-columns
  __shared__ float redh[NT*17];
  __shared__ float redm[128*17];
  __shared__ float sprod[B_SZ*9];
  __shared__ float ssh[B_SZ];
  __shared__ float bwl[8], hel[8], btl[4];

  for (int idx = tid; idx < 896*8; idx += NT) {
    int k = idx >> 3, jj = idx & 7;
    float v;
    if (k < 512)      v = Wh[(size_t)k*U_SZ + JH + jj];
    else if (k < 768) v = Wmm[(size_t)(k-512)*U_SZ + JH + jj];
    else              v = Wi[(size_t)(k-768)*U_SZ + JH + jj];
    Wl[idx] = v;
  }
  for (int idx = tid; idx < N_SZ*4; idx += NT) {
    int k = idx >> 2, jj = idx & 3;
    Aml[idx] = Amw[(size_t)k*N_SZ + JM + jj];
  }
  if (tid < 8) { bwl[tid] = bww[JH + tid]; hel[tid] = he[JH + tid]; }
  if (tid < 4) btl[tid] = btv[JM + tid];
  __syncthreads();

  const float4* Wl4  = (const float4*)Wl;
  const float4* Aml4 = (const float4*)Aml;

  for (int t = 0; t < T_LEN; ++t) {
    const float* S  = Sb + (size_t)(t & 1)*(768*B_SZ);
    float*       Sn = Sb + (size_t)((t+1) & 1)*(768*B_SZ);

    if (tid < B_SZ) ssh[tid] = ss[(t % 3)*B_SZ + tid];
    if (g == 0 && tid < B_SZ && (t + 2) < T_LEN)
      ss[((t + 2) % 3)*B_SZ + tid] = uxw[(size_t)(t+2)*B_SZ + tid];   // reset future slot
    __syncthreads();

    float4 a0={0,0,0,0}, a1={0,0,0,0}, a2={0,0,0,0}, a3={0,0,0,0};
    float4 q0={0,0,0,0}, q1={0,0,0,0}, q2={0,0,0,0}, q3={0,0,0,0};

    // seg1: k in [0,512): h-state x Wh
    #pragma unroll 4
    for (int i = 0; i < 32; ++i) {
      int kk = i*16 + ks;
      float4 sv = *(const float4*)(S + (size_t)kk*B_SZ + b0);
      float4 wv = Wl4[kk*2 + jt];
      FMA4(a0, sv.x, wv) FMA4(a1, sv.y, wv) FMA4(a2, sv.z, wv) FMA4(a3, sv.w, wv)
    }
    // seg2: k in [512,768): m-state x Wmm, plus m-state x Am (m update)
    #pragma unroll 2
    for (int i = 32; i < 48; ++i) {
      int kk = i*16 + ks;
      float4 sv = *(const float4*)(S + (size_t)kk*B_SZ + b0);
      float4 wv = Wl4[kk*2 + jt];
      FMA4(a0, sv.x, wv) FMA4(a1, sv.y, wv) FMA4(a2, sv.z, wv) FMA4(a3, sv.w, wv)
      float4 av = Aml4[kk - 512];
      FMA4(q0, sv.x, av) FMA4(q1, sv.y, av) FMA4(q2, sv.z, av) FMA4(q3, sv.w, av)
    }
    // seg3: x_t x Wi (fused xk)
    const float* xrow = xT + (size_t)t*D_IN*B_SZ;
    #pragma unroll 2
    for (int i = 48; i < 56; ++i) {
      int kk = i*16 + ks;
      float4 sv = *(const float4*)(xrow + (size_t)(kk - 768)*B_SZ + b0);
      float4 wv = Wl4[kk*2 + jt];
      FMA4(a0, sv.x, wv) FMA4(a1, sv.y, wv) FMA4(a2, sv.z, wv) FMA4(a3, sv.w, wv)
    }

    // write split-K partials (stride-17 layout: conflict-light)
    {
      float* rp = redh + tid*17;
      rp[0]=a0.x;  rp[1]=a0.y;  rp[2]=a0.z;  rp[3]=a0.w;
      rp[4]=a1.x;  rp[5]=a1.y;  rp[6]=a1.z;  rp[7]=a1.w;
      rp[8]=a2.x;  rp[9]=a2.y;  rp[10]=a2.z; rp[11]=a2.w;
      rp[12]=a3.x; rp[13]=a3.y; rp[14]=a3.z; rp[15]=a3.w;
      if (jt == 0) {
        float* rm = redm + (bt + 8*ks)*17;
        rm[0]=q0.x;  rm[1]=q0.y;  rm[2]=q0.z;  rm[3]=q0.w;
        rm[4]=q1.x;  rm[5]=q1.y;  rm[6]=q1.z;  rm[7]=q1.w;
        rm[8]=q2.x;  rm[9]=q2.y;  rm[10]=q2.z; rm[11]=q2.w;
        rm[12]=q3.x; rm[13]=q3.y; rm[14]=q3.z; rm[15]=q3.w;
      }
    }
    __syncthreads();

    // reduce + epilogue
    {
      int o = tid;
      int jj = o & 7, b = o >> 3;
      int xi = b & 3, bto = b >> 2, jto = jj >> 2, y = jj & 3;
      int base = bto + 8*jto;
      float sum = 0.f;
      #pragma unroll
      for (int k2 = 0; k2 < 16; ++k2)
        sum += redh[(base + 16*k2)*17 + xi*4 + y];
      float sb = ssh[b];
      float val = tanhf(sum + sb*bwl[jj]);
      out[((size_t)b*T_LEN + t)*U_SZ + JH + jj] = val;
      Sn[(size_t)(JH + jj)*B_SZ + b] = val;
      sprod[b*9 + jj] = val * hel[jj];
      if (tid < 128) {
        int jm = tid & 3, bm = tid >> 2;
        int xm = bm & 3, btm = bm >> 2;
        float sm = 0.f;
        #pragma unroll
        for (int k2 = 0; k2 < 16; ++k2)
          sm += redm[(btm + 8*k2)*17 + xm*4 + jm];
        sm += ssh[bm]*btl[jm];
        Sn[(size_t)(512 + JM + jm)*B_SZ + bm] = sm;
      }
    }
    __syncthreads();

    // accumulate s_{t+1} partial from own h' slice
    if (tid < B_SZ) {
      float sp = 0.f;
      #pragma unroll
      for (int jj = 0; jj < 8; ++jj) sp += sprod[tid*9 + jj];
      if (t + 1 < T_LEN) atomicAdd(&ss[((t + 1) % 3)*B_SZ + tid], sp);
    }

    // grid barrier (monotonic counter, agent-scope release/acquire for cross-XCD)
    __syncthreads();
    if (tid == 0) {
      __builtin_amdgcn_fence(__ATOMIC_RELEASE, "agent");
      __hip_atomic_fetch_add(cnt, 1u, __ATOMIC_RELAXED, __HIP_MEMORY_SCOPE_AGENT);
      unsigned target = (unsigned)(t + 1) * GS;
      while (__hip_atomic_load(cnt, __ATOMIC_RELAXED, __HIP_MEMORY_SCOPE_AGENT) < target)
        __builtin_amdgcn_s_sleep(2);
      __builtin_amdgcn_fence(__ATOMIC_ACQUIRE, "agent");
    }
    __syncthreads();
  }
}

extern "C" void kernel_launch(void* const* d_in, const int* in_sizes, int n_in,
                              void* d_out, int out_size, void* d_ws, size_t ws_size,
                              hipStream_t stream) {
  const float* x   = (const float*)d_in[0];
  const float* h0  = (const float*)d_in[1];
  const float* m0  = (const float*)d_in[2];
  const float* ie  = (const float*)d_in[3];
  const float* he  = (const float*)d_in[4];
  const float* me  = (const float*)d_in[5];
  const float* Wi  = (const float*)d_in[6];
  const float* Wh  = (const float*)d_in[7];
  const float* Wm  = (const float*)d_in[8];
  const float* AT  = (const float*)d_in[9];
  const float* BT  = (const float*)d_in[10];
  float* ws  = (float*)d_ws;
  float* out = (float*)d_out;

  k_am  <<<N_SZ, 256, 0, stream>>>(AT, me, BT, ws);
  k_bw  <<<2, 256, 0, stream>>>(BT, Wm, ws);
  k_wmm <<<N_SZ, 256, 0, stream>>>(Wm, ws);
  k_ux  <<<T_LEN, 256, 0, stream>>>(x, ie, ws);
  k_xt  <<<T_LEN*4, 256, 0, stream>>>(x, ws);
  k_init<<<25, 256, 0, stream>>>(h0, m0, he, ws);
  k_scan<<<GS, NT, 0, stream>>>(Wh, Wi, he, BT, ws, out);
}

// Round 2
// 18138.934 us; speedup vs baseline: 1.3356x; 1.3356x over previous
//
#include <hip/hip_runtime.h>
#include <math.h>

#define T_LEN 2048
#define B_SZ  32
#define D_IN  128
#define U_SZ  512
#define N_SZ  256
#define GS    64
#define NT    256

// workspace offsets (in floats)
constexpr size_t OFF_AM  = 0;                                  // Am [256][256]
constexpr size_t OFF_WMM = OFF_AM  + (size_t)N_SZ*N_SZ;        // Wmm [256][512]
constexpr size_t OFF_BW  = OFF_WMM + (size_t)N_SZ*U_SZ;        // bw [512]
constexpr size_t OFF_UX  = OFF_BW  + U_SZ;                     // ux [2048][32]
constexpr size_t OFF_XT  = OFF_UX  + (size_t)T_LEN*B_SZ;       // xT [2048][128][32]
constexpr size_t OFF_S   = OFF_XT  + (size_t)T_LEN*D_IN*B_SZ;  // S [2][768][32]
constexpr size_t OFF_SP  = OFF_S   + (size_t)2*768*B_SZ;       // sp [2][64][32]
constexpr size_t OFF_BAR = OFF_SP  + (size_t)2*GS*B_SZ + 32;   // barrier counter (padded line)

#define FMA4(A, S0, W0) \
  A.x = fmaf(S0, W0.x, A.x); A.y = fmaf(S0, W0.y, A.y); \
  A.z = fmaf(S0, W0.z, A.z); A.w = fmaf(S0, W0.w, A.w);

// ---- fence-free cross-XCD primitives: sc1 (agent-scope) loads/stores bypass L2 ----
__device__ inline float2 ld_agent_f2(const float* p) {
  unsigned long long v = __hip_atomic_load((const unsigned long long*)p,
                                           __ATOMIC_RELAXED, __HIP_MEMORY_SCOPE_AGENT);
  union { unsigned long long u; float2 f; } c; c.u = v; return c.f;
}
__device__ inline void st_agent_f2(float* p, float2 f) {
  union { float2 f; unsigned long long u; } c; c.f = f;
  __hip_atomic_store((unsigned long long*)p, c.u,
                     __ATOMIC_RELAXED, __HIP_MEMORY_SCOPE_AGENT);
}
__device__ inline void st_agent_f1(float* p, float f) {
  union { float f; unsigned u; } c; c.f = f;
  __hip_atomic_store((unsigned*)p, c.u, __ATOMIC_RELAXED, __HIP_MEMORY_SCOPE_AGENT);
}

// Am[k][j] = AT[k][j] + I + me[k]*BT[j]
__global__ void k_am(const float* __restrict__ AT, const float* __restrict__ me,
                     const float* __restrict__ BT, float* __restrict__ ws) {
  int k = blockIdx.x, j = threadIdx.x;
  float v = AT[(size_t)k*N_SZ + j] + (k == j ? 1.0f : 0.0f) + me[k]*BT[j];
  ws[OFF_AM + (size_t)k*N_SZ + j] = v;
}

// bw[j] = sum_q BT[q]*Wm[q][j]
__global__ void k_bw(const float* __restrict__ BT, const float* __restrict__ Wm,
                     float* __restrict__ ws) {
  int j = blockIdx.x*256 + threadIdx.x;
  float acc = 0.f;
  for (int q = 0; q < N_SZ; ++q) acc += BT[q]*Wm[(size_t)q*U_SZ + j];
  ws[OFF_BW + j] = acc;
}

// Wmm = Am @ Wm   [256][512]
__global__ void k_wmm(const float* __restrict__ Wm, float* __restrict__ ws) {
  __shared__ float amr[N_SZ];
  int k = blockIdx.x, tid = threadIdx.x;
  amr[tid] = ws[OFF_AM + (size_t)k*N_SZ + tid];
  __syncthreads();
  float acc0 = 0.f, acc1 = 0.f;
  for (int q = 0; q < N_SZ; ++q) {
    float a = amr[q];
    acc0 += a * Wm[(size_t)q*U_SZ + tid];
    acc1 += a * Wm[(size_t)q*U_SZ + tid + 256];
  }
  ws[OFF_WMM + (size_t)k*U_SZ + tid]       = acc0;
  ws[OFF_WMM + (size_t)k*U_SZ + tid + 256] = acc1;
}

// ux[t][b] = x[b][t][:] . ie
__global__ void k_ux(const float* __restrict__ x, const float* __restrict__ ie,
                     float* __restrict__ ws) {
  __shared__ __align__(16) float iel[D_IN];
  __shared__ float red[B_SZ*9];
  int t = blockIdx.x, tid = threadIdx.x;
  if (tid < D_IN) iel[tid] = ie[tid];
  __syncthreads();
  int b = tid >> 3, p = tid & 7;
  const float4* xr = (const float4*)(x + ((size_t)b*T_LEN + t)*D_IN);
  const float4* wr = (const float4*)iel;
  float s = 0.f;
  for (int q = 0; q < 4; ++q) {
    int fi = p + q*8;
    float4 v = xr[fi];
    float4 w = wr[fi];
    s += v.x*w.x + v.y*w.y + v.z*w.z + v.w*w.w;
  }
  red[b*9 + p] = s;
  __syncthreads();
  if (tid < B_SZ) {
    float acc = 0.f;
    for (int p2 = 0; p2 < 8; ++p2) acc += red[tid*9 + p2];
    ws[OFF_UX + (size_t)t*B_SZ + tid] = acc;
  }
}

// xT[t][d][b] = x[b][t][d]
__global__ void k_xt(const float* __restrict__ x, float* __restrict__ ws) {
  __shared__ float tile[B_SZ*33];
  int bid = blockIdx.x;
  int t = bid >> 2, d0 = (bid & 3)*32;
  int tid = threadIdx.x;
  int lo = tid & 31, hi = tid >> 5;
  for (int p = 0; p < 4; ++p) {
    int b = hi + p*8;
    tile[b*33 + lo] = x[((size_t)b*T_LEN + t)*D_IN + d0 + lo];
  }
  __syncthreads();
  float* dst = ws + OFF_XT + ((size_t)t*D_IN + d0)*B_SZ;
  for (int p = 0; p < 4; ++p) {
    int d = hi + p*8;
    dst[(size_t)d*B_SZ + lo] = tile[lo*33 + d];
  }
}

// init S[0] = [h0 | m0] in [k][b]; sp[0][0][:]=h0.he, sp[0][1..63][:]=0; barrier=0
__global__ void k_init(const float* __restrict__ h0, const float* __restrict__ mm0,
                       const float* __restrict__ he, float* __restrict__ ws) {
  int bid = blockIdx.x, tid = threadIdx.x;
  if (bid < 24) {
    for (int i = 0; i < 4; ++i) {
      int e = bid*1024 + i*256 + tid;
      int k = e >> 5, b = e & 31;
      float v = (k < U_SZ) ? h0[(size_t)b*U_SZ + k] : mm0[(size_t)b*N_SZ + (k - U_SZ)];
      ws[OFF_S + e] = v;
    }
  } else {
    __shared__ float red[B_SZ*9];
    int b = tid >> 3, p = tid & 7;
    float s = 0.f;
    for (int i = 0; i < 64; ++i) {
      int k = p*64 + i;
      s += h0[(size_t)b*U_SZ + k] * he[k];
    }
    red[b*9 + p] = s;
    for (int idx = 32 + tid; idx < GS*B_SZ; idx += 256) ws[OFF_SP + idx] = 0.f;
    __syncthreads();
    if (tid < B_SZ) {
      float acc = 0.f;
      for (int p2 = 0; p2 < 8; ++p2) acc += red[tid*9 + p2];
      ws[OFF_SP + tid] = acc;   // g=0 slot of sp[0]
    }
    if (tid == 128) ((unsigned*)(ws + OFF_BAR))[0] = 0u;
  }
}

// persistent scan: G=64 blocks; weights in LDS; state exchanged via sc1 (agent)
// loads/stores that bypass the non-coherent per-XCD L2 -> NO per-step cache
// fences; barrier = s_waitcnt vmcnt(0) + relaxed monotonic counter.
__global__ __launch_bounds__(NT, 1) void k_scan(
    const float* __restrict__ Wh, const float* __restrict__ Wi,
    const float* __restrict__ he, const float* __restrict__ btv,
    float* __restrict__ ws, float* __restrict__ out)
{
  const int g = blockIdx.x, tid = threadIdx.x;
  const int JH = g*8, JM = g*4;
  const int bt = tid & 7, jt = (tid >> 3) & 1, ks = tid >> 4;
  const int b0 = bt*4;
  const int be = tid & 31, je = tid >> 5;      // epilogue mapping (coalesced state stores)
  const int b2 = tid & 15, gg = tid >> 4;      // sp-reduction mapping

  float* Amw = ws + OFF_AM;
  float* Wmm = ws + OFF_WMM;
  float* bww = ws + OFF_BW;
  float* uxw = ws + OFF_UX;
  float* xT  = ws + OFF_XT;
  float* Sb  = ws + OFF_S;
  float* spw = ws + OFF_SP;
  unsigned* cnt = (unsigned*)(ws + OFF_BAR);

  __shared__ __align__(16) float Wl[896*8];
  __shared__ __align__(16) float Aml[N_SZ*4];
  __shared__ float redh[NT*17];
  __shared__ float redm[128*17];
  __shared__ float redS[16*32];   // [gg][b] s-partials
  __shared__ float sprod[B_SZ*9];
  __shared__ float bwl[8], hel[8], btl[4];

  for (int idx = tid; idx < 896*8; idx += NT) {
    int k = idx >> 3, jj = idx & 7;
    float v;
    if (k < 512)      v = Wh[(size_t)k*U_SZ + JH + jj];
    else if (k < 768) v = Wmm[(size_t)(k-512)*U_SZ + JH + jj];
    else              v = Wi[(size_t)(k-768)*U_SZ + JH + jj];
    Wl[idx] = v;
  }
  for (int idx = tid; idx < N_SZ*4; idx += NT) {
    int k = idx >> 2, jj = idx & 3;
    Aml[idx] = Amw[(size_t)k*N_SZ + JM + jj];
  }
  if (tid < 8) { bwl[tid] = bww[JH + tid]; hel[tid] = he[JH + tid]; }
  if (tid < 4) btl[tid] = btv[JM + tid];
  __syncthreads();

  const float4* Wl4  = (const float4*)Wl;
  const float4* Aml4 = (const float4*)Aml;

  float4 a0={0,0,0,0}, a1={0,0,0,0}, a2={0,0,0,0}, a3={0,0,0,0};
  // seg3 for t=0 (x_0 @ Wi), local data only
  {
    const float* xrow = xT;
    #pragma unroll 2
    for (int i = 48; i < 56; ++i) {
      int kk = i*16 + ks;
      float4 sv = *(const float4*)(xrow + (size_t)(kk - 768)*B_SZ + b0);
      float4 wv = Wl4[kk*2 + jt];
      FMA4(a0, sv.x, wv) FMA4(a1, sv.y, wv) FMA4(a2, sv.z, wv) FMA4(a3, sv.w, wv)
    }
  }

  for (int t = 0; t < T_LEN; ++t) {
    const float* S  = Sb + (size_t)(t & 1)*(768*B_SZ);
    float*       Sn = Sb + (size_t)((t+1) & 1)*(768*B_SZ);

    // issue s-partial loads (cross-block, sc1) + ux early; reduce later
    float2 spacc = {0.f, 0.f};
    {
      const float* spr = spw + (size_t)(t & 1)*(GS*B_SZ);
      #pragma unroll
      for (int q = 0; q < 4; ++q) {
        float2 v = ld_agent_f2(spr + (size_t)(gg*4 + q)*B_SZ + b2*2);
        spacc.x += v.x; spacc.y += v.y;
      }
    }
    float uxv = uxw[(size_t)t*B_SZ + be];

    float4 q0={0,0,0,0}, q1={0,0,0,0}, q2={0,0,0,0}, q3={0,0,0,0};

    // seg1: k in [0,512): h x Wh   (state via sc1 loads, weights via LDS)
    #pragma unroll 4
    for (int i = 0; i < 32; ++i) {
      int kk = i*16 + ks;
      const float* sp0 = S + (size_t)kk*B_SZ + b0;
      float2 s01 = ld_agent_f2(sp0);
      float2 s23 = ld_agent_f2(sp0 + 2);
      float4 wv = Wl4[kk*2 + jt];
      FMA4(a0, s01.x, wv) FMA4(a1, s01.y, wv) FMA4(a2, s23.x, wv) FMA4(a3, s23.y, wv)
    }
    // seg2: k in [512,768): m x Wmm  +  m x Am
    #pragma unroll 2
    for (int i = 32; i < 48; ++i) {
      int kk = i*16 + ks;
      const float* sp0 = S + (size_t)kk*B_SZ + b0;
      float2 s01 = ld_agent_f2(sp0);
      float2 s23 = ld_agent_f2(sp0 + 2);
      float4 wv = Wl4[kk*2 + jt];
      FMA4(a0, s01.x, wv) FMA4(a1, s01.y, wv) FMA4(a2, s23.x, wv) FMA4(a3, s23.y, wv)
      float4 av = Aml4[kk - 512];
      FMA4(q0, s01.x, av) FMA4(q1, s01.y, av) FMA4(q2, s23.x, av) FMA4(q3, s23.y, av)
    }

    // split-K partials to LDS
    {
      float* rp = redh + tid*17;
      rp[0]=a0.x;  rp[1]=a0.y;  rp[2]=a0.z;  rp[3]=a0.w;
      rp[4]=a1.x;  rp[5]=a1.y;  rp[6]=a1.z;  rp[7]=a1.w;
      rp[8]=a2.x;  rp[9]=a2.y;  rp[10]=a2.z; rp[11]=a2.w;
      rp[12]=a3.x; rp[13]=a3.y; rp[14]=a3.z; rp[15]=a3.w;
      if (jt == 0) {
        float* rm = redm + (bt + 8*ks)*17;
        rm[0]=q0.x;  rm[1]=q0.y;  rm[2]=q0.z;  rm[3]=q0.w;
        rm[4]=q1.x;  rm[5]=q1.y;  rm[6]=q1.z;  rm[7]=q1.w;
        rm[8]=q2.x;  rm[9]=q2.y;  rm[10]=q2.z; rm[11]=q2.w;
        rm[12]=q3.x; rm[13]=q3.y; rm[14]=q3.z; rm[15]=q3.w;
      }
      // s partials
      redS[gg*B_SZ + b2*2]     = spacc.x;
      redS[gg*B_SZ + b2*2 + 1] = spacc.y;
    }
    __syncthreads();   // (A)

    // epilogue: (be, je) h-output; (be, jm) m-output for tid<128
    {
      float ssb = uxv;
      #pragma unroll
      for (int g2 = 0; g2 < 16; ++g2) ssb += redS[g2*B_SZ + be];

      int base = (be >> 2) + 8*(je >> 2);
      int off  = (be & 3)*4 + (je & 3);
      float sumh = 0.f;
      #pragma unroll
      for (int k2 = 0; k2 < 16; ++k2)
        sumh += redh[(base + 16*k2)*17 + off];
      float val = tanhf(sumh + ssb*bwl[je]);
      out[((size_t)be*T_LEN + t)*U_SZ + JH + je] = val;
      st_agent_f1(Sn + (size_t)(JH + je)*B_SZ + be, val);
      sprod[be*9 + je] = val * hel[je];

      if (tid < 128) {
        int jm = tid >> 5;
        int basem = (be >> 2);
        int offm  = (be & 3)*4 + jm;
        float summ = 0.f;
        #pragma unroll
        for (int k2 = 0; k2 < 16; ++k2)
          summ += redm[(basem + 8*k2)*17 + offm];
        summ += ssb*btl[jm];
        st_agent_f1(Sn + (size_t)(512 + JM + jm)*B_SZ + be, summ);
      }
    }
    __syncthreads();   // (B) — drains each wave's sc1 stores (vmcnt(0) before s_barrier)

    // own s-partial for t+1 (wave0 lanes; drained by lane0's vmcnt below)
    if (tid < 16) {
      float sx = 0.f, sy = 0.f;
      #pragma unroll
      for (int jj = 0; jj < 8; ++jj) {
        sx += sprod[(2*tid)*9 + jj];
        sy += sprod[(2*tid + 1)*9 + jj];
      }
      float2 f2 = {sx, sy};
      st_agent_f2(spw + (size_t)((t+1) & 1)*(GS*B_SZ) + (size_t)g*B_SZ + tid*2, f2);
    }
    if (tid == 0) {
      asm volatile("s_waitcnt vmcnt(0)" ::: "memory");
      __hip_atomic_fetch_add(cnt, 1u, __ATOMIC_RELAXED, __HIP_MEMORY_SCOPE_AGENT);
    }

    // overlap: seg3 (x_{t+1} @ Wi) while other blocks arrive
    a0={0,0,0,0}; a1={0,0,0,0}; a2={0,0,0,0}; a3={0,0,0,0};
    if (t + 1 < T_LEN) {
      const float* xrow = xT + (size_t)(t+1)*D_IN*B_SZ;
      #pragma unroll 2
      for (int i = 48; i < 56; ++i) {
        int kk = i*16 + ks;
        float4 sv = *(const float4*)(xrow + (size_t)(kk - 768)*B_SZ + b0);
        float4 wv = Wl4[kk*2 + jt];
        FMA4(a0, sv.x, wv) FMA4(a1, sv.y, wv) FMA4(a2, sv.z, wv) FMA4(a3, sv.w, wv)
      }
    }
    if (tid == 0) {
      unsigned target = (unsigned)(t + 1)*GS;
      while (__hip_atomic_load(cnt, __ATOMIC_RELAXED, __HIP_MEMORY_SCOPE_AGENT) < target)
        __builtin_amdgcn_s_sleep(1);
    }
    __syncthreads();   // (C)
    asm volatile("" ::: "memory");
  }
}

extern "C" void kernel_launch(void* const* d_in, const int* in_sizes, int n_in,
                              void* d_out, int out_size, void* d_ws, size_t ws_size,
                              hipStream_t stream) {
  const float* x   = (const float*)d_in[0];
  const float* h0  = (const float*)d_in[1];
  const float* m0  = (const float*)d_in[2];
  const float* ie  = (const float*)d_in[3];
  const float* he  = (const float*)d_in[4];
  const float* me  = (const float*)d_in[5];
  const float* Wi  = (const float*)d_in[6];
  const float* Wh  = (const float*)d_in[7];
  const float* Wm  = (const float*)d_in[8];
  const float* AT  = (const float*)d_in[9];
  const float* BT  = (const float*)d_in[10];
  float* ws  = (float*)d_ws;
  float* out = (float*)d_out;

  k_am  <<<N_SZ, 256, 0, stream>>>(AT, me, BT, ws);
  k_bw  <<<2, 256, 0, stream>>>(BT, Wm, ws);
  k_wmm <<<N_SZ, 256, 0, stream>>>(Wm, ws);
  k_ux  <<<T_LEN, 256, 0, stream>>>(x, ie, ws);
  k_xt  <<<T_LEN*4, 256, 0, stream>>>(x, ws);
  k_init<<<25, 256, 0, stream>>>(h0, m0, he, ws);
  k_scan<<<GS, NT, 0, stream>>>(Wh, Wi, he, BT, ws, out);
}

// Round 3
// 11320.576 us; speedup vs baseline: 2.1400x; 1.6023x over previous
//
#include <hip/hip_runtime.h>
#include <math.h>

#define T_LEN 2048
#define B_SZ  32
#define D_IN  128
#define U_SZ  512
#define N_SZ  256
#define GS    64
#define NT    512

// workspace offsets (in floats)
constexpr size_t OFF_AM  = 0;                                  // Am [256][256]
constexpr size_t OFF_WMM = OFF_AM  + (size_t)N_SZ*N_SZ;        // Wmm [256][512]
constexpr size_t OFF_BW  = OFF_WMM + (size_t)N_SZ*U_SZ;        // bw [512]
constexpr size_t OFF_UX  = OFF_BW  + U_SZ;                     // ux [2048][32]
constexpr size_t OFF_XT  = OFF_UX  + (size_t)T_LEN*B_SZ;       // xT [2048][128][32]
constexpr size_t OFF_S   = OFF_XT  + (size_t)T_LEN*D_IN*B_SZ;  // S [2][768][32]
constexpr size_t OFF_FLG = OFF_S   + (size_t)2*768*B_SZ;       // flags [64][16]

#define FMA4(A, S0, W0) \
  A.x = fmaf(S0, W0.x, A.x); A.y = fmaf(S0, W0.y, A.y); \
  A.z = fmaf(S0, W0.z, A.z); A.w = fmaf(S0, W0.w, A.w);

// ---- fence-free cross-XCD primitives: sc1 (agent-scope) ops bypass the
// non-coherent per-XCD L2 and are served at the device coherence point ----
__device__ inline float2 ld_agent_f2(const float* p) {
  unsigned long long v = __hip_atomic_load((const unsigned long long*)p,
                                           __ATOMIC_RELAXED, __HIP_MEMORY_SCOPE_AGENT);
  union { unsigned long long u; float2 f; } c; c.u = v; return c.f;
}
__device__ inline void st_agent_f1(float* p, float f) {
  union { float f; unsigned u; } c; c.f = f;
  __hip_atomic_store((unsigned*)p, c.u, __ATOMIC_RELAXED, __HIP_MEMORY_SCOPE_AGENT);
}

// Am[k][j] = AT[k][j] + I + me[k]*BT[j]   (folds m@me term of u into m-recurrence)
__global__ void k_am(const float* __restrict__ AT, const float* __restrict__ me,
                     const float* __restrict__ BT, float* __restrict__ ws) {
  int k = blockIdx.x, j = threadIdx.x;
  float v = AT[(size_t)k*N_SZ + j] + (k == j ? 1.0f : 0.0f) + me[k]*BT[j];
  ws[OFF_AM + (size_t)k*N_SZ + j] = v;
}

// bw[j] = sum_q BT[q]*Wm[q][j]
__global__ void k_bw(const float* __restrict__ BT, const float* __restrict__ Wm,
                     float* __restrict__ ws) {
  int j = blockIdx.x*256 + threadIdx.x;
  float acc = 0.f;
  for (int q = 0; q < N_SZ; ++q) acc += BT[q]*Wm[(size_t)q*U_SZ + j];
  ws[OFF_BW + j] = acc;
}

// Wmm = Am @ Wm   [256][512]
__global__ void k_wmm(const float* __restrict__ Wm, float* __restrict__ ws) {
  __shared__ float amr[N_SZ];
  int k = blockIdx.x, tid = threadIdx.x;
  amr[tid] = ws[OFF_AM + (size_t)k*N_SZ + tid];
  __syncthreads();
  float acc0 = 0.f, acc1 = 0.f;
  for (int q = 0; q < N_SZ; ++q) {
    float a = amr[q];
    acc0 += a * Wm[(size_t)q*U_SZ + tid];
    acc1 += a * Wm[(size_t)q*U_SZ + tid + 256];
  }
  ws[OFF_WMM + (size_t)k*U_SZ + tid]       = acc0;
  ws[OFF_WMM + (size_t)k*U_SZ + tid + 256] = acc1;
}

// ux[t][b] = x[b][t][:] . ie
__global__ void k_ux(const float* __restrict__ x, const float* __restrict__ ie,
                     float* __restrict__ ws) {
  __shared__ __align__(16) float iel[D_IN];
  __shared__ float red[B_SZ*9];
  int t = blockIdx.x, tid = threadIdx.x;
  if (tid < D_IN) iel[tid] = ie[tid];
  __syncthreads();
  int b = tid >> 3, p = tid & 7;
  const float4* xr = (const float4*)(x + ((size_t)b*T_LEN + t)*D_IN);
  const float4* wr = (const float4*)iel;
  float s = 0.f;
  for (int q = 0; q < 4; ++q) {
    int fi = p + q*8;
    float4 v = xr[fi];
    float4 w = wr[fi];
    s += v.x*w.x + v.y*w.y + v.z*w.z + v.w*w.w;
  }
  red[b*9 + p] = s;
  __syncthreads();
  if (tid < B_SZ) {
    float acc = 0.f;
    for (int p2 = 0; p2 < 8; ++p2) acc += red[tid*9 + p2];
    ws[OFF_UX + (size_t)t*B_SZ + tid] = acc;
  }
}

// xT[t][d][b] = x[b][t][d]
__global__ void k_xt(const float* __restrict__ x, float* __restrict__ ws) {
  __shared__ float tile[B_SZ*33];
  int bid = blockIdx.x;
  int t = bid >> 2, d0 = (bid & 3)*32;
  int tid = threadIdx.x;
  int lo = tid & 31, hi = tid >> 5;
  for (int p = 0; p < 4; ++p) {
    int b = hi + p*8;
    tile[b*33 + lo] = x[((size_t)b*T_LEN + t)*D_IN + d0 + lo];
  }
  __syncthreads();
  float* dst = ws + OFF_XT + ((size_t)t*D_IN + d0)*B_SZ;
  for (int p = 0; p < 4; ++p) {
    int d = hi + p*8;
    dst[(size_t)d*B_SZ + lo] = tile[lo*33 + d];
  }
}

// init: S[0] = [h0 | m0] in [k][b]; zero the barrier flags
__global__ void k_init(const float* __restrict__ h0, const float* __restrict__ mm0,
                       float* __restrict__ ws) {
  int bid = blockIdx.x, tid = threadIdx.x;
  if (bid < 24) {
    for (int i = 0; i < 4; ++i) {
      int e = bid*1024 + i*256 + tid;
      int k = e >> 5, b = e & 31;
      float v = (k < U_SZ) ? h0[(size_t)b*U_SZ + k] : mm0[(size_t)b*N_SZ + (k - U_SZ)];
      ws[OFF_S + e] = v;
    }
  } else {
    for (int idx = tid; idx < GS*16; idx += 256) ws[OFF_FLG + idx] = 0.0f;  // 0u bits
  }
}

// persistent scan: GS=64 blocks x NT=512 threads (2 waves/SIMD).
// Block g owns h-cols [g*8, g*8+8) and m-cols [g*4, g*4+4).
// Weights in LDS; state exchanged via sc1 loads/stores (no fences);
// s_t computed locally from the h-rows every block loads anyway;
// barrier = per-block epoch flag stores + wave0 per-lane poll.
__global__ __launch_bounds__(NT, 2) void k_scan(
    const float* __restrict__ Wh, const float* __restrict__ Wi,
    const float* __restrict__ he, const float* __restrict__ btv,
    float* __restrict__ ws, float* __restrict__ out)
{
  const int g = blockIdx.x, tid = threadIdx.x;
  const int JH = g*8, JM = g*4;
  const int bt = tid & 7, jt = (tid >> 3) & 1, ks = tid >> 4;   // ks in [0,32)
  const int b0 = bt*4;

  float* uxw = ws + OFF_UX;
  float* xT  = ws + OFF_XT;
  float* Sb  = ws + OFF_S;
  unsigned* flags = (unsigned*)(ws + OFF_FLG);

  __shared__ __align__(16) float Wl[896*8];   // [k][jj]: k<512 Wh, <768 Wmm, <896 Wi
  __shared__ __align__(16) float Aml[N_SZ*4]; // [k][jj] m-columns of Am
  __shared__ float Hl[U_SZ];                  // hidden_encoders
  __shared__ float redh[NT*17];
  __shared__ float redm[256*17];
  __shared__ float reds[256*9];
  __shared__ float bwl[8], btl[4];

  for (int idx = tid; idx < 896*8; idx += NT) {
    int k = idx >> 3, jj = idx & 7;
    float v;
    if (k < 512)      v = Wh[(size_t)k*U_SZ + JH + jj];
    else if (k < 768) v = ws[OFF_WMM + (size_t)(k-512)*U_SZ + JH + jj];
    else              v = Wi[(size_t)(k-768)*U_SZ + JH + jj];
    Wl[idx] = v;
  }
  for (int idx = tid; idx < N_SZ*4; idx += NT) {
    int k = idx >> 2, jj = idx & 3;
    Aml[idx] = ws[OFF_AM + (size_t)k*N_SZ + JM + jj];
  }
  for (int idx = tid; idx < U_SZ; idx += NT) Hl[idx] = he[idx];
  if (tid < 8) bwl[tid] = ws[OFF_BW + JH + tid];
  if (tid < 4) btl[tid] = btv[JM + tid];
  __syncthreads();

  const float4* Wl4  = (const float4*)Wl;
  const float4* Aml4 = (const float4*)Aml;

  float4 a0={0,0,0,0}, a1={0,0,0,0}, a2={0,0,0,0}, a3={0,0,0,0};
  // seg3 for t=0 (x_0 @ Wi), local data only
  {
    const float* xrow = xT;
    #pragma unroll
    for (int i = 24; i < 28; ++i) {
      int kk = i*32 + ks;
      float4 sv = *(const float4*)(xrow + (size_t)(kk - 768)*B_SZ + b0);
      float4 wv = Wl4[kk*2 + jt];
      FMA4(a0, sv.x, wv) FMA4(a1, sv.y, wv) FMA4(a2, sv.z, wv) FMA4(a3, sv.w, wv)
    }
  }

  for (int t = 0; t < T_LEN; ++t) {
    const float* S  = Sb + (size_t)(t & 1)*(768*B_SZ);
    float*       Sn = Sb + (size_t)((t+1) & 1)*(768*B_SZ);

    float uxv = uxw[(size_t)t*B_SZ + (tid & 31)];

    float4 q0={0,0,0,0}, q1={0,0,0,0}, q2={0,0,0,0}, q3={0,0,0,0};
    float4 sa={0,0,0,0};

    // seg1: k in [0,512): h x Wh (+ local s-partial h.he)
    #pragma unroll 8
    for (int i = 0; i < 16; ++i) {
      int kk = i*32 + ks;
      const float* sp0 = S + (size_t)kk*B_SZ + b0;
      float2 s01 = ld_agent_f2(sp0);
      float2 s23 = ld_agent_f2(sp0 + 2);
      float4 wv = Wl4[kk*2 + jt];
      float hv = Hl[kk];
      FMA4(a0, s01.x, wv) FMA4(a1, s01.y, wv) FMA4(a2, s23.x, wv) FMA4(a3, s23.y, wv)
      sa.x = fmaf(s01.x, hv, sa.x); sa.y = fmaf(s01.y, hv, sa.y);
      sa.z = fmaf(s23.x, hv, sa.z); sa.w = fmaf(s23.y, hv, sa.w);
    }
    // seg2: k in [512,768): m x Wmm  +  m x Am
    #pragma unroll 8
    for (int i = 16; i < 24; ++i) {
      int kk = i*32 + ks;
      const float* sp0 = S + (size_t)kk*B_SZ + b0;
      float2 s01 = ld_agent_f2(sp0);
      float2 s23 = ld_agent_f2(sp0 + 2);
      float4 wv = Wl4[kk*2 + jt];
      FMA4(a0, s01.x, wv) FMA4(a1, s01.y, wv) FMA4(a2, s23.x, wv) FMA4(a3, s23.y, wv)
      float4 av = Aml4[kk - 512];
      FMA4(q0, s01.x, av) FMA4(q1, s01.y, av) FMA4(q2, s23.x, av) FMA4(q3, s23.y, av)
    }

    // partials to LDS
    {
      float* rp = redh + tid*17;
      rp[0]=a0.x;  rp[1]=a0.y;  rp[2]=a0.z;  rp[3]=a0.w;
      rp[4]=a1.x;  rp[5]=a1.y;  rp[6]=a1.z;  rp[7]=a1.w;
      rp[8]=a2.x;  rp[9]=a2.y;  rp[10]=a2.z; rp[11]=a2.w;
      rp[12]=a3.x; rp[13]=a3.y; rp[14]=a3.z; rp[15]=a3.w;
      if (jt == 0) {
        int idx = bt + 8*ks;
        float* rm = redm + idx*17;
        rm[0]=q0.x;  rm[1]=q0.y;  rm[2]=q0.z;  rm[3]=q0.w;
        rm[4]=q1.x;  rm[5]=q1.y;  rm[6]=q1.z;  rm[7]=q1.w;
        rm[8]=q2.x;  rm[9]=q2.y;  rm[10]=q2.z; rm[11]=q2.w;
        rm[12]=q3.x; rm[13]=q3.y; rm[14]=q3.z; rm[15]=q3.w;
        float* rs = reds + idx*9;
        rs[0]=sa.x; rs[1]=sa.y; rs[2]=sa.z; rs[3]=sa.w;
      }
    }
    __syncthreads();   // (A)

    // epilogue: tid<256 -> h-cols (be,je); tid in [256,384) -> m-cols (be,jm)
    float val = 0.f;
    if (tid < 384) {
      const int be2 = tid & 31, btb = be2 >> 2, xx = be2 & 3;
      float ssb = uxv;
      #pragma unroll
      for (int k2 = 0; k2 < 32; ++k2) ssb += reds[(btb + 8*k2)*9 + xx];
      if (tid < 256) {
        const int je = tid >> 5, jt2 = je >> 2, yy = je & 3;
        float sum = 0.f;
        #pragma unroll
        for (int k2 = 0; k2 < 32; ++k2)
          sum += redh[(btb + 8*jt2 + 16*k2)*17 + xx*4 + yy];
        val = tanhf(sum + ssb*bwl[je]);
        st_agent_f1(Sn + (size_t)(JH + je)*B_SZ + be2, val);
      } else {
        const int jm = (tid - 256) >> 5;
        float sum = 0.f;
        #pragma unroll
        for (int k2 = 0; k2 < 32; ++k2)
          sum += redm[(btb + 8*k2)*17 + xx*4 + jm];
        sum += ssb*btl[jm];
        st_agent_f1(Sn + (size_t)(512 + JM + jm)*B_SZ + be2, sum);
      }
    }
    __syncthreads();   // (B) — implicit vmcnt(0): all Sn sc1 stores are at IC

    // arrival flag ASAP, then off-critical-path work in the barrier shadow
    if (t + 1 < T_LEN && tid == 0)
      __hip_atomic_store(flags + (size_t)g*16, (unsigned)(t + 1),
                         __ATOMIC_RELAXED, __HIP_MEMORY_SCOPE_AGENT);
    if (tid < 256)
      out[((size_t)(tid & 31)*T_LEN + t)*U_SZ + JH + (tid >> 5)] = val;

    a0.x=a0.y=a0.z=a0.w=0.f; a1=a0; a2=a0; a3=a0;
    if (t + 1 < T_LEN) {
      const float* xrow = xT + (size_t)(t+1)*D_IN*B_SZ;
      #pragma unroll
      for (int i = 24; i < 28; ++i) {
        int kk = i*32 + ks;
        float4 sv = *(const float4*)(xrow + (size_t)(kk - 768)*B_SZ + b0);
        float4 wv = Wl4[kk*2 + jt];
        FMA4(a0, sv.x, wv) FMA4(a1, sv.y, wv) FMA4(a2, sv.z, wv) FMA4(a3, sv.w, wv)
      }
      if (tid < 64) {
        const unsigned* fp = flags + (size_t)tid*16;
        while (__hip_atomic_load(fp, __ATOMIC_RELAXED, __HIP_MEMORY_SCOPE_AGENT)
               < (unsigned)(t + 1)) { }
      }
    }
    __syncthreads();   // (C)
  }
}

extern "C" void kernel_launch(void* const* d_in, const int* in_sizes, int n_in,
                              void* d_out, int out_size, void* d_ws, size_t ws_size,
                              hipStream_t stream) {
  const float* x   = (const float*)d_in[0];
  const float* h0  = (const float*)d_in[1];
  const float* m0  = (const float*)d_in[2];
  const float* ie  = (const float*)d_in[3];
  const float* he  = (const float*)d_in[4];
  const float* me  = (const float*)d_in[5];
  const float* Wi  = (const float*)d_in[6];
  const float* Wh  = (const float*)d_in[7];
  const float* Wm  = (const float*)d_in[8];
  const float* AT  = (const float*)d_in[9];
  const float* BT  = (const float*)d_in[10];
  float* ws  = (float*)d_ws;
  float* out = (float*)d_out;

  k_am  <<<N_SZ, 256, 0, stream>>>(AT, me, BT, ws);
  k_bw  <<<2, 256, 0, stream>>>(BT, Wm, ws);
  k_wmm <<<N_SZ, 256, 0, stream>>>(Wm, ws);
  k_ux  <<<T_LEN, 256, 0, stream>>>(x, ie, ws);
  k_xt  <<<T_LEN*4, 256, 0, stream>>>(x, ws);
  k_init<<<25, 256, 0, stream>>>(h0, m0, ws);
  k_scan<<<GS, NT, 0, stream>>>(Wh, Wi, he, BT, ws, out);
}